// Round 5
// baseline (1558.275 us; speedup 1.0000x reference)
//
#include <hip/hip_runtime.h>
#include <hip/hip_bf16.h>

typedef unsigned short u16;
typedef __attribute__((ext_vector_type(4))) float f32x4;
typedef __attribute__((ext_vector_type(8))) short short8;
typedef __attribute__((ext_vector_type(8))) u16 us8;

// Geometry (fixed): B=64, N=256, DIM=2048, H=8, D=256; M=B*N=16384; qkvN=6144
// Per-head planes: [512][256][256]

__device__ __forceinline__ u16 f2bf(float f) {
  union { float f; unsigned u; } v; v.f = f;
  unsigned r = v.u + 0x7fffu + ((v.u >> 16) & 1u);   // RNE, finite inputs
  return (u16)(r >> 16);
}
__device__ __forceinline__ float bf2f(u16 h) {
  union { unsigned u; float f; } v; v.u = ((unsigned)h) << 16; return v.f;
}

__global__ void beacon_kernel(float* __restrict__ out, float val, int n) {
  int stride = gridDim.x * blockDim.x;
  for (int i = blockIdx.x * blockDim.x + threadIdx.x; i < n; i += stride)
    out[i] = val;
}

__global__ void split_kernel(const float* __restrict__ in, u16* __restrict__ hi,
                             u16* __restrict__ lo, int n4) {
  int stride = gridDim.x * blockDim.x;
  for (int i = blockIdx.x * blockDim.x + threadIdx.x; i < n4; i += stride) {
    f32x4 v = ((const f32x4*)in)[i];
    ushort4 h;
    h.x = f2bf(v[0]); h.y = f2bf(v[1]); h.z = f2bf(v[2]); h.w = f2bf(v[3]);
    ((ushort4*)hi)[i] = h;
    if (lo) {
      ushort4 l;
      l.x = f2bf(v[0] - bf2f(h.x)); l.y = f2bf(v[1] - bf2f(h.y));
      l.z = f2bf(v[2] - bf2f(h.z)); l.w = f2bf(v[3] - bf2f(h.w));
      ((ushort4*)lo)[i] = l;
    }
  }
}

// ============ plain bf16 NT GEMM, m97 structure (HW-validated rounds 2 & 4) ============
// C[M,N] = sum over K of A[M,K]*B[N,K]^T, BK=32, 128x128 tile, 4 waves.
// K concatenates up to 3 segments (split-bf16 compensation as plain GEMM).
// NEW vs round 4 (speed only, math bit-identical):
//  - LDS bank-conflict fix: short8 slot swizzled by ((row>>1)&3) on BOTH the
//    global_load_lds source column (pre-swizzle) and the ds_read slot (rule 21).
//    8-way conflict -> 2-way (free).
//  - SWZ=1: flat 1D grid with XCD-bijective remap (m-major per XCD) for L3/L2
//    locality on the big GEMMs (nwg % 8 == 0 holds for all SWZ launches).
// EPI 0: qkv->q,k scatter (hi+lo); EPI 1: qkv->v plane; EPI 2: logits fp32 S;
// EPI 3: PV -> bf16 attn; EPI 4: proj -> fp32 out + bias.
template<int EPI, int SWZ>
__global__ __launch_bounds__(256)
void gemm_nt(const u16* __restrict__ A0, const u16* __restrict__ A1, const u16* __restrict__ A2,
             const u16* __restrict__ B0, const u16* __restrict__ B1, const u16* __restrict__ B2,
             u16* __restrict__ qh, u16* __restrict__ ql,
             u16* __restrict__ kh, u16* __restrict__ kl,
             u16* __restrict__ vv,
             float* __restrict__ sout, u16* __restrict__ aout,
             float* __restrict__ fout, const float* __restrict__ bias,
             int ldA, int ldB, int ksteps, int segShift, int plane_base, int gridMx) {
  __shared__ __align__(16) u16 lds[8192];   // 2 slots x [128][32] bf16
  u16* sA = lds;
  u16* sB = lds + 4096;

  const int tid = threadIdx.x;
  const int wave = tid >> 6, lane = tid & 63;
  const int wr = wave >> 1, wc = wave & 1;
  const int l15 = lane & 15, l16 = lane >> 4;
  const int sxor = (l15 >> 1) & 3;          // read-side slot swizzle (row-derived)

  size_t zoffA = 0, zoffB = 0;
  if constexpr (EPI == 2) {
    size_t gz = (size_t)(plane_base + blockIdx.z) * 65536;
    zoffA = gz; zoffB = gz;
  }
  if constexpr (EPI == 3) {
    zoffA = (size_t)blockIdx.z * 65536;                 // P: group-local plane
    zoffB = (size_t)(plane_base + blockIdx.z) * 65536;  // vT: global plane
  }
  const u16* As[3] = {A0 + zoffA, A1 + zoffA, A2 + zoffA};
  const u16* Bs[3] = {B0 + zoffB, B1 + zoffB, B2 + zoffB};

  int m0, n0;
  if constexpr (SWZ) {
    int bid = blockIdx.x, cpx = gridDim.x >> 3;
    int swz = (bid & 7) * cpx + (bid >> 3);   // bijective when nwg % 8 == 0
    m0 = (swz % gridMx) << 7;
    n0 = (swz / gridMx) << 7;
  } else {
    m0 = blockIdx.x << 7;
    n0 = blockIdx.y << 7;
  }
  const int kmask = (1 << segShift) - 1;

  f32x4 acc[4][4] = {};

  // stage a [128][32] tile; LDS dest linear, global col pre-swizzled so the
  // swizzled ds_read sees natural data.  slot' = slot ^ ((row>>1)&3).
  auto stage = [&](const u16* gp, int ld, u16* slot, int row0, int k0) {
    int scol = ((lane & 3) ^ ((lane >> 3) & 3)) * 8;   // pre-swizzled col group
    #pragma unroll
    for (int c = 0; c < 2; ++c) {
      int chunk = wave + c * 4;
      int r = chunk * 16 + (lane >> 2);
      const u16* src = gp + (size_t)(row0 + r) * ld + (k0 + scol);
      __builtin_amdgcn_global_load_lds(
          (const __attribute__((address_space(1))) unsigned*)src,
          (__attribute__((address_space(3))) unsigned*)(slot + chunk * 512), 16, 0, 0);
    }
  };

  for (int ks = 0; ks < ksteps; ++ks) {
    int seg = ks >> segShift;
    int k0 = (ks & kmask) * 32;
    stage(As[seg], ldA, sA, m0, k0);
    stage(Bs[seg], ldB, sB, n0, k0);
    __syncthreads();

    short8 a[4], b[4];
    #pragma unroll
    for (int i = 0; i < 4; ++i) {
      int ra = (wr * 64 + i * 16 + l15) * 4 + (l16 ^ sxor);   // swizzled slot
      int rb = (wc * 64 + i * 16 + l15) * 4 + (l16 ^ sxor);
      a[i] = ((const short8*)sA)[ra];
      b[i] = ((const short8*)sB)[rb];
    }
    #pragma unroll
    for (int i = 0; i < 4; ++i)
      #pragma unroll
      for (int j = 0; j < 4; ++j)
        acc[i][j] = __builtin_amdgcn_mfma_f32_16x16x32_bf16(a[i], b[j], acc[i][j], 0, 0, 0);
    __syncthreads();
  }

  // epilogue: C/D layout (m89/m91): col = lane&15, row = (lane>>4)*4 + reg
  #pragma unroll
  for (int i = 0; i < 4; ++i)
    #pragma unroll
    for (int j = 0; j < 4; ++j)
      #pragma unroll
      for (int r = 0; r < 4; ++r) {
        int gm = m0 + wr * 64 + i * 16 + l16 * 4 + r;
        int gn = n0 + wc * 64 + j * 16 + l15;
        float val = acc[i][j][r];
        if constexpr (EPI == 0) {
          int b = gm >> 8, tok = gm & 255;
          int sel = gn >> 11, head = (gn >> 8) & 7, col = gn & 255;
          size_t addr = (((size_t)b * 8 + head) * 256 + tok) * 256 + col;
          u16 h = f2bf(val), lo = f2bf(val - bf2f(h));
          if (sel == 0) { qh[addr] = h; ql[addr] = lo; }
          else          { kh[addr] = h; kl[addr] = lo; }
        } else if constexpr (EPI == 1) {
          int b = gm >> 8, tok = gm & 255;
          int head = (gn >> 8) & 7, col = gn & 255;
          size_t addr = (((size_t)b * 8 + head) * 256 + tok) * 256 + col;
          vv[addr] = f2bf(val);
        } else if constexpr (EPI == 2) {
          sout[(size_t)blockIdx.z * 65536 + (size_t)gm * 256 + gn] = val;
        } else if constexpr (EPI == 3) {
          int gp = plane_base + blockIdx.z;
          size_t row = (size_t)(gp >> 3) * 256 + gm;
          size_t col = (size_t)(gp & 7) * 256 + gn;
          aout[row * 2048 + col] = f2bf(val);
        } else {
          fout[(size_t)gm * 2048 + gn] = val + bias[gn];
        }
      }
}

// ---------- per-head 256x256 in-place transpose (k_hi, k_lo, v) ----------
__global__ void transpose_inplace(u16* __restrict__ kh, u16* __restrict__ kl,
                                  u16* __restrict__ v) {
  __shared__ u16 ta[64][66], tb[64][66];
  u16* base = (blockIdx.z == 0) ? kh : (blockIdx.z == 1) ? kl : v;
  u16* pl = base + (size_t)blockIdx.y * 65536;
  const int RA[10] = {0,1,2,3, 0,0,0,1,1,2};
  const int CA[10] = {0,1,2,3, 1,2,3,2,3,3};
  int p = blockIdx.x;
  int R = RA[p], C = CA[p];
  bool diag = (R == C);
  int tid = threadIdx.x;
  int r = tid >> 2, c0 = (tid & 3) * 16;

  const us8* sa = (const us8*)(pl + (size_t)(R * 64 + r) * 256 + C * 64 + c0);
  us8 a0 = sa[0], a1 = sa[1];
  #pragma unroll
  for (int s = 0; s < 8; ++s) { ta[r][c0 + s] = a0[s]; ta[r][c0 + 8 + s] = a1[s]; }
  if (!diag) {
    const us8* sb = (const us8*)(pl + (size_t)(C * 64 + r) * 256 + R * 64 + c0);
    us8 b0 = sb[0], b1 = sb[1];
    #pragma unroll
    for (int s = 0; s < 8; ++s) { tb[r][c0 + s] = b0[s]; tb[r][c0 + 8 + s] = b1[s]; }
  }
  __syncthreads();
  us8 o0, o1;
  #pragma unroll
  for (int s = 0; s < 8; ++s) { o0[s] = ta[c0 + s][r]; o1[s] = ta[c0 + 8 + s][r]; }
  us8* da = (us8*)(pl + (size_t)(C * 64 + r) * 256 + R * 64 + c0);
  da[0] = o0; da[1] = o1;
  if (!diag) {
    us8 p0, p1;
    #pragma unroll
    for (int s = 0; s < 8; ++s) { p0[s] = tb[c0 + s][r]; p1[s] = tb[c0 + 8 + s][r]; }
    us8* db = (us8*)(pl + (size_t)(R * 64 + r) * 256 + C * 64 + c0);
    db[0] = p0; db[1] = p1;
  }
}

// ---------- row softmax over 256 fp32 -> bf16 P; one wave per row ----------
__global__ void softmax_kernel(const float* __restrict__ S, u16* __restrict__ P) {
  int row = blockIdx.x * 4 + (threadIdx.x >> 6);
  int lane = threadIdx.x & 63;
  f32x4 v = ((const f32x4*)(S + (size_t)row * 256))[lane];
  float mx = fmaxf(fmaxf(v[0], v[1]), fmaxf(v[2], v[3]));
  #pragma unroll
  for (int o = 32; o > 0; o >>= 1) mx = fmaxf(mx, __shfl_xor(mx, o));
  float e0 = __expf(v[0] - mx), e1 = __expf(v[1] - mx);
  float e2 = __expf(v[2] - mx), e3 = __expf(v[3] - mx);
  float sum = e0 + e1 + e2 + e3;
  #pragma unroll
  for (int o = 32; o > 0; o >>= 1) sum += __shfl_xor(sum, o);
  float inv = 1.0f / sum;
  ushort4 p;
  p.x = f2bf(e0 * inv); p.y = f2bf(e1 * inv); p.z = f2bf(e2 * inv); p.w = f2bf(e3 * inv);
  ((ushort4*)(P + (size_t)row * 256))[lane] = p;
}

extern "C" void kernel_launch(void* const* d_in, const int* in_sizes, int n_in,
                              void* d_out, int out_size, void* d_ws, size_t ws_size,
                              hipStream_t stream) {
  const float* x  = (const float*)d_in[0];   // [16384, 2048]
  const float* wq = (const float*)d_in[1];   // [6144, 2048]
  const float* wp = (const float*)d_in[2];   // [2048, 2048]
  const float* bp = (const float*)d_in[3];   // [2048]
  float* out = (float*)d_out;
  char* ws = (char*)d_ws;

  const size_t MB = 1ull << 20;
  const size_t NEED = 432 * MB;
  if (ws_size < NEED) {
    beacon_kernel<<<2048, 256, 0, stream>>>(out, (float)(ws_size >> 20), 16384 * 2048);
    return;
  }

  // persistent per-head tensors [0, 320 MiB)
  u16* q_hi = (u16*)(ws);
  u16* q_lo = (u16*)(ws + 64 * MB);
  u16* k_hi = (u16*)(ws + 128 * MB);
  u16* k_lo = (u16*)(ws + 192 * MB);
  u16* vbuf = (u16*)(ws + 256 * MB);
  // G1 phase window [320, 432 MiB)
  u16* x_hi = (u16*)(ws + 320 * MB);   // 64 MiB (no x_lo needed)
  u16* w_hi = (u16*)(ws + 384 * MB);   // 24 MiB
  u16* w_lo = (u16*)(ws + 408 * MB);   // 24 MiB
  // attention phase window (x, w dead)
  float* S  = (float*)(ws + 320 * MB); // 32 MiB
  u16* Pm   = (u16*)(ws + 352 * MB);   // 16 MiB
  u16* attn = (u16*)(ws + 368 * MB);   // 64 MiB (lives into proj)
  u16* wpb  = (u16*)(ws + 320 * MB);   //  8 MiB (over dead S)

  // prep: x -> hi only; w_qkv -> hi+lo
  split_kernel<<<8192, 256, 0, stream>>>(x,  x_hi, nullptr, 16384 * 2048 / 4);
  split_kernel<<<4096, 256, 0, stream>>>(wq, w_hi, w_lo, 6144 * 2048 / 4);

  // G1 qk: q,k = x_hi @ (w_hi + w_lo)^T  (2 K-segments of 2048); XCD-swizzled flat grid
  gemm_nt<0, 1><<<4096, 256, 0, stream>>>(
      x_hi, x_hi, x_hi, w_hi, w_lo, w_hi,
      q_hi, q_lo, k_hi, k_lo, nullptr, nullptr, nullptr, nullptr, nullptr,
      2048, 2048, 128, 6, 0, 128);
  // G1 v: v = x_hi @ wv_hi^T  (1 segment)
  const u16* wv = w_hi + (size_t)4096 * 2048;
  gemm_nt<1, 1><<<2048, 256, 0, stream>>>(
      x_hi, x_hi, x_hi, wv, wv, wv,
      nullptr, nullptr, nullptr, nullptr, vbuf, nullptr, nullptr, nullptr, nullptr,
      2048, 2048, 64, 6, 0, 128);

  // in-place per-head transpose of k (hi,lo) and v
  transpose_inplace<<<dim3(10, 512, 3), 256, 0, stream>>>(k_hi, k_lo, vbuf);

  // attention in 4 groups of 128 planes
  for (int gp = 0; gp < 4; ++gp) {
    int pb = gp * 128;
    // S^T = kT*q^T, 3-term compensation as 3 K-segments of 256
    gemm_nt<2, 0><<<dim3(2, 2, 128), 256, 0, stream>>>(
        k_hi, k_hi, k_lo, q_hi, q_lo, q_hi,
        nullptr, nullptr, nullptr, nullptr, nullptr, S, nullptr, nullptr, nullptr,
        256, 256, 24, 3, pb, 0);
    softmax_kernel<<<8192, 256, 0, stream>>>(S, Pm);
    // PV: attn = P @ vT^T
    gemm_nt<3, 0><<<dim3(2, 2, 128), 256, 0, stream>>>(
        Pm, Pm, Pm, vbuf, vbuf, vbuf,
        nullptr, nullptr, nullptr, nullptr, nullptr, nullptr, attn, nullptr, nullptr,
        256, 256, 8, 3, pb, 0);
  }

  // proj: out = attn @ wp^T + bias
  split_kernel<<<2048, 256, 0, stream>>>(wp, wpb, nullptr, 2048 * 2048 / 4);
  gemm_nt<4, 1><<<2048, 256, 0, stream>>>(
      attn, attn, attn, wpb, wpb, wpb,
      nullptr, nullptr, nullptr, nullptr, nullptr, nullptr, nullptr, out, bp,
      2048, 2048, 64, 6, 0, 128);
}

// Round 6
// 1116.068 us; speedup vs baseline: 1.3962x; 1.3962x over previous
//
#include <hip/hip_runtime.h>
#include <hip/hip_bf16.h>

typedef unsigned short u16;
typedef __attribute__((ext_vector_type(4))) float f32x4;
typedef __attribute__((ext_vector_type(8))) short short8;
typedef __attribute__((ext_vector_type(8))) u16 us8;

// Geometry (fixed): B=64, N=256, DIM=2048, H=8, D=256; M=B*N=16384; qkvN=6144
// Per-head planes: [512][256][256]

__device__ __forceinline__ u16 f2bf(float f) {
  union { float f; unsigned u; } v; v.f = f;
  unsigned r = v.u + 0x7fffu + ((v.u >> 16) & 1u);   // RNE, finite inputs
  return (u16)(r >> 16);
}
__device__ __forceinline__ float bf2f(u16 h) {
  union { unsigned u; float f; } v; v.u = ((unsigned)h) << 16; return v.f;
}

__global__ void beacon_kernel(float* __restrict__ out, float val, int n) {
  int stride = gridDim.x * blockDim.x;
  for (int i = blockIdx.x * blockDim.x + threadIdx.x; i < n; i += stride)
    out[i] = val;
}

__global__ void split_kernel(const float* __restrict__ in, u16* __restrict__ hi,
                             u16* __restrict__ lo, int n4) {
  int stride = gridDim.x * blockDim.x;
  for (int i = blockIdx.x * blockDim.x + threadIdx.x; i < n4; i += stride) {
    f32x4 v = ((const f32x4*)in)[i];
    ushort4 h;
    h.x = f2bf(v[0]); h.y = f2bf(v[1]); h.z = f2bf(v[2]); h.w = f2bf(v[3]);
    ((ushort4*)hi)[i] = h;
    if (lo) {
      ushort4 l;
      l.x = f2bf(v[0] - bf2f(h.x)); l.y = f2bf(v[1] - bf2f(h.y));
      l.z = f2bf(v[2] - bf2f(h.z)); l.w = f2bf(v[3] - bf2f(h.w));
      ((ushort4*)lo)[i] = l;
    }
  }
}

#define LGKM0 do { asm volatile("s_waitcnt lgkmcnt(0)" ::: "memory"); \
                   __builtin_amdgcn_sched_barrier(0); } while (0)
#define VMDRAIN do { asm volatile("s_waitcnt vmcnt(0)" ::: "memory"); } while (0)
#define BAR __builtin_amdgcn_s_barrier()

// ============ 256x256 4-phase bf16 NT GEMM (BK=64, 8 waves 2Mx4N) ============
// C[M,N] = A[M,K']*B[N,K']^T; K' = up to 2 concatenated segments (split-bf16
// compensation as plain GEMM).  Schedule invariant: all 8 stage-loads of tile
// t+1 are issued at P1/P2 of tile t and drained by ONE vmcnt(0) before the
// P4-end barrier -> every wave's loads landed before any wave reads t+1.
// Loads stay in flight across the P1..P3 barriers (counted-wait benefit).
// LDS [256][64] bf16 per operand, slot swizzle: phys_slot = nat ^ (row&7),
// applied to BOTH global_load_lds source col and ds_read (rule 21).
// EPI 0: qkv->q,k scatter (hi+lo); EPI 1: qkv->v plane; EPI 2: proj out+bias.
template<int EPI>
__global__ __launch_bounds__(512, 2)
void gemm256(const u16* __restrict__ A0, const u16* __restrict__ A1,
             const u16* __restrict__ B0, const u16* __restrict__ B1,
             int ldA, int ldB, int ntiles, int segShift, int gridMx,
             u16* __restrict__ qh, u16* __restrict__ ql,
             u16* __restrict__ kh, u16* __restrict__ kl,
             u16* __restrict__ vv,
             float* __restrict__ fout, const float* __restrict__ bias) {
  extern __shared__ __align__(16) u16 lds[];   // 128 KiB: 2 dbuf x (A+B)[256][64]

  const int tid = threadIdx.x;
  const int w = tid >> 6, lane = tid & 63;
  const int wr = w >> 2, wcn = w & 3;          // 2M x 4N waves, 128x64 out each
  const int l15 = lane & 15, g = lane >> 4;
  const int rsw = l15 & 7;                     // read-side slot XOR (row&7)
  const int scol = (((tid & 7) ^ ((tid >> 3) & 7)) << 3);  // pre-swz src col

  // XCD-bijective swizzle (gridDim.x % 8 == 0), m-fastest per XCD
  int bid = blockIdx.x, cpx = gridDim.x >> 3;
  int swz = (bid & 7) * cpx + (bid >> 3);
  int m0 = (swz % gridMx) << 8;
  int n0 = (swz / gridMx) << 8;

  const u16* As[2] = {A0, A1};
  const u16* Bs[2] = {B0, B1};
  const int kmask = (1 << segShift) - 1;

  f32x4 acc[8][4] = {};
  short8 af[8], bA[4], bB[4];

  // stage strip s (64 rows x 64 cols) of A or B tile into LDS buf db.
  // LDS dest linear (wave-uniform base + lane*16B); source col pre-swizzled.
  auto stageA = [&](int db, const u16* Ab, int k0) {
    #pragma unroll
    for (int s = 0; s < 4; ++s) {
      const u16* src = Ab + (size_t)(m0 + s * 64 + (tid >> 3)) * ldA + k0 + scol;
      u16* dst = lds + db * 32768 + s * 4096 + tid * 8;
      __builtin_amdgcn_global_load_lds(
          (const __attribute__((address_space(1))) unsigned*)src,
          (__attribute__((address_space(3))) unsigned*)dst, 16, 0, 0);
    }
  };
  auto stageB = [&](int db, const u16* Bb, int k0) {
    #pragma unroll
    for (int s = 0; s < 4; ++s) {
      const u16* src = Bb + (size_t)(n0 + s * 64 + (tid >> 3)) * ldB + k0 + scol;
      u16* dst = lds + db * 32768 + 16384 + s * 4096 + tid * 8;
      __builtin_amdgcn_global_load_lds(
          (const __attribute__((address_space(1))) unsigned*)src,
          (__attribute__((address_space(3))) unsigned*)dst, 16, 0, 0);
    }
  };
  auto readA = [&](int db, int MH) {   // 8 x ds_read_b128 -> af
    #pragma unroll
    for (int f = 0; f < 4; ++f) {
      int row = wr * 128 + MH * 64 + f * 16 + l15;
      #pragma unroll
      for (int kk = 0; kk < 2; ++kk) {
        int sl = (kk * 4 + g) ^ rsw;
        af[f * 2 + kk] = *(const short8*)(lds + db * 32768 + row * 64 + sl * 8);
      }
    }
  };
  auto readB = [&](short8* bf, int db, int NH) {  // 4 x ds_read_b128
    #pragma unroll
    for (int f = 0; f < 2; ++f) {
      int row = wcn * 64 + NH * 32 + f * 16 + l15;
      #pragma unroll
      for (int kk = 0; kk < 2; ++kk) {
        int sl = (kk * 4 + g) ^ rsw;
        bf[f * 2 + kk] = *(const short8*)(lds + db * 32768 + 16384 + row * 64 + sl * 8);
      }
    }
  };

#define MMA_QUAD(MH, NH, BF)                                                   \
  __builtin_amdgcn_s_setprio(1);                                               \
  _Pragma("unroll") for (int f = 0; f < 4; ++f)                                \
    _Pragma("unroll") for (int j = 0; j < 2; ++j)                              \
      _Pragma("unroll") for (int kk = 0; kk < 2; ++kk)                         \
        acc[(MH) * 4 + f][(NH) * 2 + j] =                                      \
            __builtin_amdgcn_mfma_f32_16x16x32_bf16(                           \
                af[f * 2 + kk], BF[j * 2 + kk],                                \
                acc[(MH) * 4 + f][(NH) * 2 + j], 0, 0, 0);                     \
  __builtin_amdgcn_s_setprio(0)

  const int T = ntiles;
  // prologue: tile 0 fully staged, fully drained
  stageA(0, As[0], 0);
  stageB(0, Bs[0], 0);
  VMDRAIN;
  BAR;
  __builtin_amdgcn_sched_barrier(0);

  for (int t = 0; t < T - 1; ++t) {
    int cur = t & 1, nxt = cur ^ 1;
    int t1 = t + 1;
    const u16* An = As[t1 >> segShift];
    const u16* Bn = Bs[t1 >> segShift];
    int kn = (t1 & kmask) << 6;
    // P1: quadrant (0,0); issue all A stages of t+1
    readA(cur, 0);
    readB(bA, cur, 0);
    stageA(nxt, An, kn);
    BAR; LGKM0;
    MMA_QUAD(0, 0, bA);
    BAR; __builtin_amdgcn_sched_barrier(0);
    // P2: quadrant (0,1); issue all B stages of t+1
    readB(bB, cur, 1);
    stageB(nxt, Bn, kn);
    BAR; LGKM0;
    MMA_QUAD(0, 1, bB);
    BAR; __builtin_amdgcn_sched_barrier(0);
    // P3: quadrant (1,1) (bB resident)
    readA(cur, 1);
    BAR; LGKM0;
    MMA_QUAD(1, 1, bB);
    BAR; __builtin_amdgcn_sched_barrier(0);
    // P4: quadrant (1,0) (bA resident); drain t+1 loads, then barrier
    MMA_QUAD(1, 0, bA);
    VMDRAIN;
    BAR; __builtin_amdgcn_sched_barrier(0);
  }
  {  // peeled last tile: reads only
    int cur = (T - 1) & 1;
    readA(cur, 0);
    readB(bA, cur, 0);
    LGKM0;
    MMA_QUAD(0, 0, bA);
    readB(bB, cur, 1);
    LGKM0;
    MMA_QUAD(0, 1, bB);
    readA(cur, 1);
    LGKM0;
    MMA_QUAD(1, 1, bB);
    MMA_QUAD(1, 0, bA);
  }
#undef MMA_QUAD

  // epilogue: C/D layout (m89/m91): col = lane&15, row = (lane>>4)*4 + reg
  #pragma unroll
  for (int i = 0; i < 8; ++i)
    #pragma unroll
    for (int j = 0; j < 4; ++j)
      #pragma unroll
      for (int rr = 0; rr < 4; ++rr) {
        int gm = m0 + wr * 128 + i * 16 + g * 4 + rr;
        int gn = n0 + wcn * 64 + j * 16 + l15;
        float val = acc[i][j][rr];
        if constexpr (EPI == 0) {
          int b = gm >> 8, tok = gm & 255;
          int sel = gn >> 11, head = (gn >> 8) & 7, col = gn & 255;
          size_t addr = (((size_t)b * 8 + head) * 256 + tok) * 256 + col;
          u16 h = f2bf(val), lo = f2bf(val - bf2f(h));
          if (sel == 0) { qh[addr] = h; ql[addr] = lo; }
          else          { kh[addr] = h; kl[addr] = lo; }
        } else if constexpr (EPI == 1) {
          int b = gm >> 8, tok = gm & 255;
          int head = (gn >> 8) & 7, col = gn & 255;
          size_t addr = (((size_t)b * 8 + head) * 256 + tok) * 256 + col;
          vv[addr] = f2bf(val);
        } else {
          fout[(size_t)gm * 2048 + gn] = val + bias[gn];
        }
      }
}

// ============ plain bf16 NT GEMM (m97 structure, HW-validated) — G2/G3 ============
template<int EPI, int SWZ>
__global__ __launch_bounds__(256)
void gemm_nt(const u16* __restrict__ A0, const u16* __restrict__ A1, const u16* __restrict__ A2,
             const u16* __restrict__ B0, const u16* __restrict__ B1, const u16* __restrict__ B2,
             float* __restrict__ sout, u16* __restrict__ aout,
             int ksteps, int segShift, int plane_base) {
  __shared__ __align__(16) u16 lds[8192];   // 2 slots x [128][32] bf16
  u16* sA = lds;
  u16* sB = lds + 4096;

  const int tid = threadIdx.x;
  const int wave = tid >> 6, lane = tid & 63;
  const int wr = wave >> 1, wc = wave & 1;
  const int l15 = lane & 15, l16 = lane >> 4;
  const int sxor = (l15 >> 1) & 3;

  size_t zoffA = 0, zoffB = 0;
  if constexpr (EPI == 2) {
    size_t gz = (size_t)(plane_base + blockIdx.z) * 65536;
    zoffA = gz; zoffB = gz;
  }
  if constexpr (EPI == 3) {
    zoffA = (size_t)blockIdx.z * 65536;
    zoffB = (size_t)(plane_base + blockIdx.z) * 65536;
  }
  const u16* As[3] = {A0 + zoffA, A1 + zoffA, A2 + zoffA};
  const u16* Bs[3] = {B0 + zoffB, B1 + zoffB, B2 + zoffB};

  const int m0 = blockIdx.x << 7;
  const int n0 = blockIdx.y << 7;
  const int kmask = (1 << segShift) - 1;

  f32x4 acc[4][4] = {};

  auto stage = [&](const u16* gp, int ld, u16* slot, int row0, int k0) {
    int scol = ((lane & 3) ^ ((lane >> 3) & 3)) * 8;
    #pragma unroll
    for (int c = 0; c < 2; ++c) {
      int chunk = wave + c * 4;
      int r = chunk * 16 + (lane >> 2);
      const u16* src = gp + (size_t)(row0 + r) * ld + (k0 + scol);
      __builtin_amdgcn_global_load_lds(
          (const __attribute__((address_space(1))) unsigned*)src,
          (__attribute__((address_space(3))) unsigned*)(slot + chunk * 512), 16, 0, 0);
    }
  };

  for (int ks = 0; ks < ksteps; ++ks) {
    int seg = ks >> segShift;
    int k0 = (ks & kmask) * 32;
    stage(As[seg], 256, sA, m0, k0);
    stage(Bs[seg], 256, sB, n0, k0);
    __syncthreads();

    short8 a[4], b[4];
    #pragma unroll
    for (int i = 0; i < 4; ++i) {
      int ra = (wr * 64 + i * 16 + l15) * 4 + (l16 ^ sxor);
      int rb = (wc * 64 + i * 16 + l15) * 4 + (l16 ^ sxor);
      a[i] = ((const short8*)sA)[ra];
      b[i] = ((const short8*)sB)[rb];
    }
    #pragma unroll
    for (int i = 0; i < 4; ++i)
      #pragma unroll
      for (int j = 0; j < 4; ++j)
        acc[i][j] = __builtin_amdgcn_mfma_f32_16x16x32_bf16(a[i], b[j], acc[i][j], 0, 0, 0);
    __syncthreads();
  }

  #pragma unroll
  for (int i = 0; i < 4; ++i)
    #pragma unroll
    for (int j = 0; j < 4; ++j)
      #pragma unroll
      for (int r = 0; r < 4; ++r) {
        int gm = m0 + wr * 64 + i * 16 + l16 * 4 + r;
        int gn = n0 + wc * 64 + j * 16 + l15;
        float val = acc[i][j][r];
        if constexpr (EPI == 2) {
          sout[(size_t)blockIdx.z * 65536 + (size_t)gm * 256 + gn] = val;
        } else {
          int gp = plane_base + blockIdx.z;
          size_t row = (size_t)(gp >> 3) * 256 + gm;
          size_t col = (size_t)(gp & 7) * 256 + gn;
          aout[row * 2048 + col] = f2bf(val);
        }
      }
}

// ---------- per-head 256x256 in-place transpose (k_hi, k_lo, v) ----------
__global__ void transpose_inplace(u16* __restrict__ kh, u16* __restrict__ kl,
                                  u16* __restrict__ v) {
  __shared__ u16 ta[64][66], tb[64][66];
  u16* base = (blockIdx.z == 0) ? kh : (blockIdx.z == 1) ? kl : v;
  u16* pl = base + (size_t)blockIdx.y * 65536;
  const int RA[10] = {0,1,2,3, 0,0,0,1,1,2};
  const int CA[10] = {0,1,2,3, 1,2,3,2,3,3};
  int p = blockIdx.x;
  int R = RA[p], C = CA[p];
  bool diag = (R == C);
  int tid = threadIdx.x;
  int r = tid >> 2, c0 = (tid & 3) * 16;

  const us8* sa = (const us8*)(pl + (size_t)(R * 64 + r) * 256 + C * 64 + c0);
  us8 a0 = sa[0], a1 = sa[1];
  #pragma unroll
  for (int s = 0; s < 8; ++s) { ta[r][c0 + s] = a0[s]; ta[r][c0 + 8 + s] = a1[s]; }
  if (!diag) {
    const us8* sb = (const us8*)(pl + (size_t)(C * 64 + r) * 256 + R * 64 + c0);
    us8 b0 = sb[0], b1 = sb[1];
    #pragma unroll
    for (int s = 0; s < 8; ++s) { tb[r][c0 + s] = b0[s]; tb[r][c0 + 8 + s] = b1[s]; }
  }
  __syncthreads();
  us8 o0, o1;
  #pragma unroll
  for (int s = 0; s < 8; ++s) { o0[s] = ta[c0 + s][r]; o1[s] = ta[c0 + 8 + s][r]; }
  us8* da = (us8*)(pl + (size_t)(C * 64 + r) * 256 + R * 64 + c0);
  da[0] = o0; da[1] = o1;
  if (!diag) {
    us8 p0, p1;
    #pragma unroll
    for (int s = 0; s < 8; ++s) { p0[s] = tb[c0 + s][r]; p1[s] = tb[c0 + 8 + s][r]; }
    us8* db = (us8*)(pl + (size_t)(R * 64 + r) * 256 + C * 64 + c0);
    db[0] = p0; db[1] = p1;
  }
}

// ---------- row softmax over 256 fp32 -> bf16 P; one wave per row ----------
__global__ void softmax_kernel(const float* __restrict__ S, u16* __restrict__ P) {
  int row = blockIdx.x * 4 + (threadIdx.x >> 6);
  int lane = threadIdx.x & 63;
  f32x4 v = ((const f32x4*)(S + (size_t)row * 256))[lane];
  float mx = fmaxf(fmaxf(v[0], v[1]), fmaxf(v[2], v[3]));
  #pragma unroll
  for (int o = 32; o > 0; o >>= 1) mx = fmaxf(mx, __shfl_xor(mx, o));
  float e0 = __expf(v[0] - mx), e1 = __expf(v[1] - mx);
  float e2 = __expf(v[2] - mx), e3 = __expf(v[3] - mx);
  float sum = e0 + e1 + e2 + e3;
  #pragma unroll
  for (int o = 32; o > 0; o >>= 1) sum += __shfl_xor(sum, o);
  float inv = 1.0f / sum;
  ushort4 p;
  p.x = f2bf(e0 * inv); p.y = f2bf(e1 * inv); p.z = f2bf(e2 * inv); p.w = f2bf(e3 * inv);
  ((ushort4*)(P + (size_t)row * 256))[lane] = p;
}

extern "C" void kernel_launch(void* const* d_in, const int* in_sizes, int n_in,
                              void* d_out, int out_size, void* d_ws, size_t ws_size,
                              hipStream_t stream) {
  const float* x  = (const float*)d_in[0];   // [16384, 2048]
  const float* wq = (const float*)d_in[1];   // [6144, 2048]
  const float* wp = (const float*)d_in[2];   // [2048, 2048]
  const float* bp = (const float*)d_in[3];   // [2048]
  float* out = (float*)d_out;
  char* ws = (char*)d_ws;

  const size_t MB = 1ull << 20;
  const size_t NEED = 432 * MB;
  if (ws_size < NEED) {
    beacon_kernel<<<2048, 256, 0, stream>>>(out, (float)(ws_size >> 20), 16384 * 2048);
    return;
  }

  // persistent per-head tensors [0, 320 MiB)
  u16* q_hi = (u16*)(ws);
  u16* q_lo = (u16*)(ws + 64 * MB);
  u16* k_hi = (u16*)(ws + 128 * MB);
  u16* k_lo = (u16*)(ws + 192 * MB);
  u16* vbuf = (u16*)(ws + 256 * MB);
  // G1 phase window [320, 432 MiB)
  u16* x_hi = (u16*)(ws + 320 * MB);   // 64 MiB
  u16* w_hi = (u16*)(ws + 384 * MB);   // 24 MiB
  u16* w_lo = (u16*)(ws + 408 * MB);   // 24 MiB
  // attention phase window (x, w dead)
  float* S  = (float*)(ws + 320 * MB); // 32 MiB
  u16* Pm   = (u16*)(ws + 352 * MB);   // 16 MiB
  u16* attn = (u16*)(ws + 368 * MB);   // 64 MiB (lives into proj)
  u16* wpb  = (u16*)(ws + 320 * MB);   //  8 MiB (over dead S)

  // prep: x -> hi only; w_qkv -> hi+lo
  split_kernel<<<8192, 256, 0, stream>>>(x,  x_hi, nullptr, 16384 * 2048 / 4);
  split_kernel<<<4096, 256, 0, stream>>>(wq, w_hi, w_lo, 6144 * 2048 / 4);

  // G1 qk: q,k = x_hi @ (w_hi | w_lo)^T  (2 K-segments of 32 tiles)
  gemm256<0><<<1024, 512, 131072, stream>>>(
      x_hi, x_hi, w_hi, w_lo, 2048, 2048, 64, 5, 64,
      q_hi, q_lo, k_hi, k_lo, nullptr, nullptr, nullptr);
  // G1 v: v = x_hi @ wv_hi^T  (1 segment)
  const u16* wv = w_hi + (size_t)4096 * 2048;
  gemm256<1><<<512, 512, 131072, stream>>>(
      x_hi, x_hi, wv, wv, 2048, 2048, 32, 5, 64,
      nullptr, nullptr, nullptr, nullptr, vbuf, nullptr, nullptr);

  // in-place per-head transpose of k (hi,lo) and v
  transpose_inplace<<<dim3(10, 512, 3), 256, 0, stream>>>(k_hi, k_lo, vbuf);

  // attention in 4 groups of 128 planes
  for (int gp = 0; gp < 4; ++gp) {
    int pb = gp * 128;
    // S^T = kT*q^T, 3-term compensation as 3 K-segments of 256
    gemm_nt<2, 0><<<dim3(2, 2, 128), 256, 0, stream>>>(
        k_hi, k_hi, k_lo, q_hi, q_lo, q_hi,
        S, nullptr, 24, 3, pb);
    softmax_kernel<<<8192, 256, 0, stream>>>(S, Pm);
    // PV: attn = P @ vT^T
    gemm_nt<3, 0><<<dim3(2, 2, 128), 256, 0, stream>>>(
        Pm, Pm, Pm, vbuf, vbuf, vbuf,
        nullptr, attn, 8, 3, pb);
  }

  // proj: out = attn @ wp^T + bias
  split_kernel<<<2048, 256, 0, stream>>>(wp, wpb, nullptr, 2048 * 2048 / 4);
  gemm256<2><<<512, 512, 131072, stream>>>(
      attn, attn, wpb, wpb, 2048, 2048, 32, 5, 64,
      nullptr, nullptr, nullptr, nullptr, nullptr, out, bp);
}